// Round 8
// baseline (395.247 us; speedup 1.0000x reference)
//
#include <hip/hip_runtime.h>
#include <math.h>

#define B_   32
#define T_   1024
#define N_   77
#define D_   512
#define TD_  256
#define TE_  2048
#define H_   8
#define DH_  64

typedef short bf16x8 __attribute__((ext_vector_type(8)));
typedef float f32x4  __attribute__((ext_vector_type(4)));

__device__ __forceinline__ float sigmoidf_fast(float x) {
    return 1.0f / (1.0f + __expf(-x));
}

// float -> bf16 bits, round-to-nearest-even
__device__ __forceinline__ unsigned short f2b(float f) {
    unsigned int u = __float_as_uint(f);
    unsigned int r = u + 0x7FFFu + ((u >> 16) & 1u);
    return (unsigned short)(r >> 16);
}

// bf16 bits -> float
__device__ __forceinline__ float b2f(short us) {
    return __uint_as_float(((unsigned int)(unsigned short)us) << 16);
}

// async global->LDS 16B (wave-uniform LDS base + lane*16 required)
#define GL16(g, l) __builtin_amdgcn_global_load_lds(                         \
    (const __attribute__((address_space(1))) unsigned int*)(g),              \
    (__attribute__((address_space(3))) unsigned int*)(l), 16, 0, 0)

#define WAITV8()  asm volatile("s_waitcnt vmcnt(8)"  ::: "memory")
#define WAITV4()  asm volatile("s_waitcnt vmcnt(4)"  ::: "memory")
#define WAITV0()  asm volatile("s_waitcnt vmcnt(0)"  ::: "memory")
#define WAITL0()  asm volatile("s_waitcnt lgkmcnt(0)" ::: "memory")
#define SBAR()   __builtin_amdgcn_s_barrier()
#define SCHED0() __builtin_amdgcn_sched_barrier(0)

// ---------------------------------------------------------------------------
// xf layernorm -> bf16. One wave per 256-col row; lane holds float4.
// ---------------------------------------------------------------------------
__global__ __launch_bounds__(256) void ln_xf_kernel(
    const float* __restrict__ x, const float* __restrict__ w, const float* __restrict__ b,
    unsigned short* __restrict__ outb)
{
    int row = blockIdx.x * 4 + (threadIdx.x >> 6);
    int lane = threadIdx.x & 63;
    const float* rp = x + (size_t)row * TD_ + lane * 4;
    float4 v = *(const float4*)rp;
    float s  = v.x + v.y + v.z + v.w;
    float ss = v.x*v.x + v.y*v.y + v.z*v.z + v.w*v.w;
    #pragma unroll
    for (int off = 32; off; off >>= 1) {
        s  += __shfl_xor(s, off);
        ss += __shfl_xor(ss, off);
    }
    float m = s * (1.f / TD_);
    float r = rsqrtf(ss * (1.f / TD_) - m * m + 1e-5f);
    float4 wv = *(const float4*)(w + lane * 4);
    float4 bv = *(const float4*)(b + lane * 4);
    ushort4 o;
    o.x = f2b((v.x - m) * r * wv.x + bv.x);
    o.y = f2b((v.y - m) * r * wv.y + bv.y);
    o.z = f2b((v.z - m) * r * wv.z + bv.z);
    o.w = f2b((v.w - m) * r * wv.w + bv.w);
    *(ushort4*)(outb + (size_t)row * TD_ + lane * 4) = o;
}

// ---------------------------------------------------------------------------
// All weight fp32->bf16 converts in one launch.
// ---------------------------------------------------------------------------
__global__ __launch_bounds__(256) void conv_weights_kernel(
    const float* __restrict__ Wq, const float* __restrict__ Wout,
    const float* __restrict__ Wk, const float* __restrict__ Wv,
    unsigned short* __restrict__ wqb, unsigned short* __restrict__ wob,
    unsigned short* __restrict__ wkvb)
{
    int bid = blockIdx.x;
    const float* src; unsigned short* dst;
    if (bid < 128)      { src = Wq;   dst = wqb; }
    else if (bid < 256) { src = Wout; dst = wob;               bid -= 128; }
    else if (bid < 320) { src = Wk;   dst = wkvb;              bid -= 256; }
    else                { src = Wv;   dst = wkvb + D_ * TD_;   bid -= 320; }
    int idx = (bid * 256 + threadIdx.x) * 8;
    float4 v0 = *(const float4*)(src + idx);
    float4 v1 = *(const float4*)(src + idx + 4);
    ushort4 o0 = {f2b(v0.x), f2b(v0.y), f2b(v0.z), f2b(v0.w)};
    ushort4 o1 = {f2b(v1.x), f2b(v1.y), f2b(v1.z), f2b(v1.w)};
    *(ushort4*)(dst + idx)     = o0;
    *(ushort4*)(dst + idx + 4) = o1;
}

// ---------------------------------------------------------------------------
// Fused K+V projection, bf16 MFMA, K=256, 3-buffer counted-vmcnt pipeline
// (round-4 structure: measured best).
// ---------------------------------------------------------------------------
__global__ __launch_bounds__(256) void kv_gemm_kernel(
    const unsigned short* __restrict__ Ab,
    const unsigned short* __restrict__ Wb,
    const float* __restrict__ bkp, const float* __restrict__ bvp,
    const int*   __restrict__ cond,
    unsigned short* __restrict__ kout, unsigned short* __restrict__ vout)
{
    constexpr int K = TD_;       // 256
    constexpr int NSTEP = 8;     // K / 32
    __shared__ __align__(16) unsigned short As[3][128 * 32];
    __shared__ __align__(16) unsigned short Bs[3][128 * 32];

    const int tid  = threadIdx.x;
    int id = blockIdx.x;
    int swz = (id & 7) * 20 + (id >> 3);
    const int m0 = (swz >> 3) * 128;
    const int n0 = (swz & 7) * 128;
    const int lane = tid & 63;
    const int w    = tid >> 6;
    const int l15  = lane & 15;
    const int quad = lane >> 4;
    const int wm   = (w >> 1) * 64;
    const int wn   = (w & 1) * 64;

    const int row_a = tid >> 2;
    const int ck    = (tid & 3) ^ ((row_a >> 1) & 3);
    const int sc    = (quad ^ ((l15 >> 1) & 3)) << 3;

    f32x4 acc[4][4];
    #pragma unroll
    for (int i = 0; i < 4; i++)
        #pragma unroll
        for (int j = 0; j < 4; j++)
            acc[i][j] = (f32x4){0.f, 0.f, 0.f, 0.f};

    const char* gA = (const char*)Ab + ((size_t)(m0 + row_a) * K) * 2 + ck * 16;
    const char* gB = (const char*)Wb + ((size_t)(n0 + row_a) * K) * 2 + ck * 16;
    const size_t g2 = (size_t)64 * K * 2;
    char* lA = (char*)&As[0][0] + tid * 16;
    char* lB = (char*)&Bs[0][0] + tid * 16;

#define KSTAGE(s, buf) do {                                                   \
        GL16(gA + (s) * 64,      lA + (buf) * 8192);                          \
        GL16(gA + (s) * 64 + g2, lA + (buf) * 8192 + 4096);                   \
        GL16(gB + (s) * 64,      lB + (buf) * 8192);                          \
        GL16(gB + (s) * 64 + g2, lB + (buf) * 8192 + 4096);                   \
    } while (0)

    KSTAGE(0, 0);
    KSTAGE(1, 1);
    KSTAGE(2, 2);

    bf16x8 af[4], bfr[4];
    #pragma unroll
    for (int t = 0; t < NSTEP; t++) {
        const int cur = t % 3;
        if (t < NSTEP - 2)       { WAITV8(); }
        else if (t == NSTEP - 2) { WAITV4(); }
        else                     { WAITV0(); }
        SBAR(); SCHED0();
        #pragma unroll
        for (int i = 0; i < 4; i++)
            af[i] = *(const bf16x8*)&As[cur][(wm + i * 16 + l15) * 32 + sc];
        #pragma unroll
        for (int j = 0; j < 4; j++)
            bfr[j] = *(const bf16x8*)&Bs[cur][(wn + j * 16 + l15) * 32 + sc];
        WAITL0(); SCHED0();
        SBAR(); SCHED0();
        if (t + 3 < NSTEP) KSTAGE(t + 3, cur);
        __builtin_amdgcn_s_setprio(1);
        #pragma unroll
        for (int i = 0; i < 4; i++)
            #pragma unroll
            for (int j = 0; j < 4; j++)
                acc[i][j] = __builtin_amdgcn_mfma_f32_16x16x32_bf16(af[i], bfr[j], acc[i][j], 0, 0, 0);
        __builtin_amdgcn_s_setprio(0);
    }
#undef KSTAGE

    #pragma unroll
    for (int i = 0; i < 4; i++) {
        int mbase = m0 + wm + i * 16 + quad * 4;
        #pragma unroll
        for (int j = 0; j < 4; j++) {
            int n = n0 + wn + j * 16 + l15;
            bool isv = n >= D_;
            int nn = isv ? n - D_ : n;
            float bn = isv ? bvp[nn] : bkp[nn];
            unsigned short* outp = isv ? vout : kout;
            #pragma unroll
            for (int r = 0; r < 4; r++) {
                int m = mbase + r;
                if (m >= B_ * N_) continue;
                float v = acc[i][j][r] + bn;
                if (isv) {
                    int bi = m / N_;
                    v = ((cond[bi] % 10) > 0) ? v : 0.f;
                }
                outp[(size_t)m * D_ + nn] = f2b(v);
            }
        }
    }
}

// ---------------------------------------------------------------------------
// emb GEMM with fused silu: e[32][1024] = silu(emb)[32][2048] @ emb_w^T.
// ---------------------------------------------------------------------------
__global__ __launch_bounds__(256) void emb_gemm_kernel(
    const float* __restrict__ emb, const float* __restrict__ W,
    float* __restrict__ e)
{
    int wid = blockIdx.x * 4 + (threadIdx.x >> 6);   // 0..2047
    int lane = threadIdx.x & 63;
    int ngrp = wid >> 3;        // 0..255  (4 n each)
    int bgrp = wid & 7;         // 0..7    (4 b each)

    float acc[4][4] = {};
    #pragma unroll 2
    for (int it = 0; it < 8; it++) {
        int k = (it * 64 + lane) * 4;
        float4 sv[4], wv[4];
        #pragma unroll
        for (int bi = 0; bi < 4; bi++) {
            float4 t = *(const float4*)&emb[(size_t)(bgrp * 4 + bi) * TE_ + k];
            t.x *= sigmoidf_fast(t.x);
            t.y *= sigmoidf_fast(t.y);
            t.z *= sigmoidf_fast(t.z);
            t.w *= sigmoidf_fast(t.w);
            sv[bi] = t;
        }
        #pragma unroll
        for (int ni = 0; ni < 4; ni++)
            wv[ni] = *(const float4*)&W[(size_t)(ngrp * 4 + ni) * TE_ + k];
        #pragma unroll
        for (int bi = 0; bi < 4; bi++)
            #pragma unroll
            for (int ni = 0; ni < 4; ni++) {
                acc[bi][ni] = fmaf(sv[bi].x, wv[ni].x, acc[bi][ni]);
                acc[bi][ni] = fmaf(sv[bi].y, wv[ni].y, acc[bi][ni]);
                acc[bi][ni] = fmaf(sv[bi].z, wv[ni].z, acc[bi][ni]);
                acc[bi][ni] = fmaf(sv[bi].w, wv[ni].w, acc[bi][ni]);
            }
    }
    #pragma unroll
    for (int bi = 0; bi < 4; bi++)
        #pragma unroll
        for (int ni = 0; ni < 4; ni++) {
            float a = acc[bi][ni];
            #pragma unroll
            for (int off = 32; off; off >>= 1) a += __shfl_xor(a, off);
            if (lane == 0)
                e[(size_t)(bgrp * 4 + bi) * 1024 + ngrp * 4 + ni] = a;
        }
}

// ---------------------------------------------------------------------------
// prep_q: out_bf16 = bf16(LN(x; norm_w, norm_b)). One wave per 512-row.
// ---------------------------------------------------------------------------
__global__ __launch_bounds__(256) void prep_q_kernel(
    const float* __restrict__ x, const float* __restrict__ w, const float* __restrict__ b,
    unsigned short* __restrict__ outb)
{
    int row = blockIdx.x * 4 + (threadIdx.x >> 6);
    int lane = threadIdx.x & 63;
    const float* rp = x + (size_t)row * D_ + lane * 8;
    float4 v0 = *(const float4*)rp;
    float4 v1 = *(const float4*)(rp + 4);
    float s  = v0.x + v0.y + v0.z + v0.w + v1.x + v1.y + v1.z + v1.w;
    float ss = v0.x*v0.x + v0.y*v0.y + v0.z*v0.z + v0.w*v0.w
             + v1.x*v1.x + v1.y*v1.y + v1.z*v1.z + v1.w*v1.w;
    #pragma unroll
    for (int off = 32; off; off >>= 1) {
        s  += __shfl_xor(s, off);
        ss += __shfl_xor(ss, off);
    }
    float m = s * (1.f / D_);
    float r = rsqrtf(ss * (1.f / D_) - m * m + 1e-5f);
    float4 w0 = *(const float4*)(w + lane * 8);
    float4 w1 = *(const float4*)(w + lane * 8 + 4);
    float4 b0 = *(const float4*)(b + lane * 8);
    float4 b1 = *(const float4*)(b + lane * 8 + 4);
    ushort4 o0, o1;
    o0.x = f2b((v0.x - m) * r * w0.x + b0.x);
    o0.y = f2b((v0.y - m) * r * w0.y + b0.y);
    o0.z = f2b((v0.z - m) * r * w0.z + b0.z);
    o0.w = f2b((v0.w - m) * r * w0.w + b0.w);
    o1.x = f2b((v1.x - m) * r * w1.x + b1.x);
    o1.y = f2b((v1.y - m) * r * w1.y + b1.y);
    o1.z = f2b((v1.z - m) * r * w1.z + b1.z);
    o1.w = f2b((v1.w - m) * r * w1.w + b1.w);
    unsigned short* op = outb + (size_t)row * D_ + lane * 8;
    *(ushort4*)op       = o0;
    *(ushort4*)(op + 4) = o1;
}

// ---------------------------------------------------------------------------
// prep_h: out_bf16 = bf16( silu( LN(y)*(1+sc) + sh ) ), sc/sh = e + emb_b.
// y is bf16 (written by attn); stats computed in fp32 from bf16 values.
// ---------------------------------------------------------------------------
__global__ __launch_bounds__(256) void prep_h_kernel(
    const unsigned short* __restrict__ y, const float* __restrict__ w, const float* __restrict__ b,
    const float* __restrict__ e, const float* __restrict__ emb_b,
    unsigned short* __restrict__ outb)
{
    int row = blockIdx.x * 4 + (threadIdx.x >> 6);
    int lane = threadIdx.x & 63;
    int bb = row >> 10;
    const unsigned short* rp = y + (size_t)row * D_ + lane * 8;
    bf16x8 yv = *(const bf16x8*)rp;
    float v[8];
    #pragma unroll
    for (int k2 = 0; k2 < 8; k2++) v[k2] = b2f(yv[k2]);
    float s = 0.f, ss = 0.f;
    #pragma unroll
    for (int k2 = 0; k2 < 8; k2++) { s += v[k2]; ss += v[k2] * v[k2]; }
    #pragma unroll
    for (int off = 32; off; off >>= 1) {
        s  += __shfl_xor(s, off);
        ss += __shfl_xor(ss, off);
    }
    float m = s * (1.f / D_);
    float r = rsqrtf(ss * (1.f / D_) - m * m + 1e-5f);
    float4 w0 = *(const float4*)(w + lane * 8);
    float4 w1 = *(const float4*)(w + lane * 8 + 4);
    float4 b0 = *(const float4*)(b + lane * 8);
    float4 b1 = *(const float4*)(b + lane * 8 + 4);
    float wa[8] = {w0.x, w0.y, w0.z, w0.w, w1.x, w1.y, w1.z, w1.w};
    float ba[8] = {b0.x, b0.y, b0.z, b0.w, b1.x, b1.y, b1.z, b1.w};
    const float* ep = e + (size_t)bb * 1024 + lane * 8;
    float4 sc0 = *(const float4*)ep;
    float4 sc1 = *(const float4*)(ep + 4);
    float4 sh0 = *(const float4*)(ep + 512);
    float4 sh1 = *(const float4*)(ep + 512 + 4);
    float4 eb0 = *(const float4*)(emb_b + lane * 8);
    float4 eb1 = *(const float4*)(emb_b + lane * 8 + 4);
    float4 fb0 = *(const float4*)(emb_b + 512 + lane * 8);
    float4 fb1 = *(const float4*)(emb_b + 512 + lane * 8 + 4);
    float sca[8] = {sc0.x + eb0.x, sc0.y + eb0.y, sc0.z + eb0.z, sc0.w + eb0.w,
                    sc1.x + eb1.x, sc1.y + eb1.y, sc1.z + eb1.z, sc1.w + eb1.w};
    float sha[8] = {sh0.x + fb0.x, sh0.y + fb0.y, sh0.z + fb0.z, sh0.w + fb0.w,
                    sh1.x + fb1.x, sh1.y + fb1.y, sh1.z + fb1.z, sh1.w + fb1.w};
    ushort4 o0, o1;
    unsigned short oa[8];
    #pragma unroll
    for (int k2 = 0; k2 < 8; k2++) {
        float hv = ((v[k2] - m) * r * wa[k2] + ba[k2]) * (1.f + sca[k2]) + sha[k2];
        oa[k2] = f2b(hv * sigmoidf_fast(hv));
    }
    o0.x = oa[0]; o0.y = oa[1]; o0.z = oa[2]; o0.w = oa[3];
    o1.x = oa[4]; o1.y = oa[5]; o1.z = oa[6]; o1.w = oa[7];
    unsigned short* op = outb + (size_t)row * D_ + lane * 8;
    *(ushort4*)op       = o0;
    *(ushort4*)(op + 4) = o1;
}

// ---------------------------------------------------------------------------
// bf16 MFMA GEMM (round-4 structure, measured best): 128x128 tile, BK=32,
// 3-buffer LDS (48 KB), counted-vmcnt pipeline (vmcnt(8) steady state),
// (row>>1)&3 chunk-XOR LDS swizzle (0 conflicts), XCD-chunked block swizzle.
// ---------------------------------------------------------------------------
template <int RESID, int OUTBF>
__global__ __launch_bounds__(256) void gemm_bf16_kernel(
    const unsigned short* __restrict__ Ab,
    const unsigned short* __restrict__ Wb,
    const float* __restrict__ bias,
    const float* __restrict__ resid,
    void* __restrict__ Cv)
{
    constexpr int K = 512;
    constexpr int NSTEP = 16;    // K / 32
    __shared__ __align__(16) unsigned short As[3][128 * 32];
    __shared__ __align__(16) unsigned short Bs[3][128 * 32];

    const int tid  = threadIdx.x;
    int id = blockIdx.x;
    int swz = (id & 7) * 128 + (id >> 3);
    const int m0 = (swz >> 2) * 128;
    const int n0 = (swz & 3) * 128;
    const int lane = tid & 63;
    const int w    = tid >> 6;
    const int l15  = lane & 15;
    const int quad = lane >> 4;
    const int wm   = (w >> 1) * 64;
    const int wn   = (w & 1) * 64;

    const int row_s = tid >> 2;                        // 0..63
    const int ck    = (tid & 3) ^ ((row_s >> 1) & 3);  // swizzled source chunk
    const int sc    = (quad ^ ((l15 >> 1) & 3)) << 3;  // read-side XOR (ushorts)

    f32x4 acc[4][4];
    #pragma unroll
    for (int i = 0; i < 4; i++)
        #pragma unroll
        for (int j = 0; j < 4; j++)
            acc[i][j] = (f32x4){0.f, 0.f, 0.f, 0.f};

    const char* gA = (const char*)Ab + ((size_t)(m0 + row_s) * K) * 2 + ck * 16;
    const char* gB = (const char*)Wb + ((size_t)(n0 + row_s) * K) * 2 + ck * 16;
    const size_t g2 = (size_t)64 * K * 2;              // +64 rows
    char* lA = (char*)&As[0][0] + tid * 16;
    char* lB = (char*)&Bs[0][0] + tid * 16;

#define STAGE_G(s, buf) do {                                                  \
        GL16(gA + (s) * 64,      lA + (buf) * 8192);                          \
        GL16(gA + (s) * 64 + g2, lA + (buf) * 8192 + 4096);                   \
        GL16(gB + (s) * 64,      lB + (buf) * 8192);                          \
        GL16(gB + (s) * 64 + g2, lB + (buf) * 8192 + 4096);                   \
    } while (0)

    STAGE_G(0, 0);
    STAGE_G(1, 1);
    STAGE_G(2, 2);

    bf16x8 af[4], bfr[4];
    #pragma unroll
    for (int t = 0; t < NSTEP; t++) {
        const int cur = t % 3;
        if (t < NSTEP - 2)       { WAITV8(); }
        else if (t == NSTEP - 2) { WAITV4(); }
        else                     { WAITV0(); }
        SBAR(); SCHED0();                    // all waves' step-t loads landed
        #pragma unroll
        for (int i = 0; i < 4; i++)
            af[i] = *(const bf16x8*)&As[cur][(wm + i * 16 + l15) * 32 + sc];
        #pragma unroll
        for (int j = 0; j < 4; j++)
            bfr[j] = *(const bf16x8*)&Bs[cur][(wn + j * 16 + l15) * 32 + sc];
        WAITL0(); SCHED0();
        SBAR(); SCHED0();                    // all waves done reading buf[cur]
        if (t + 3 < NSTEP) STAGE_G(t + 3, cur);
        __builtin_amdgcn_s_setprio(1);
        #pragma unroll
        for (int i = 0; i < 4; i++)
            #pragma unroll
            for (int j = 0; j < 4; j++)
                acc[i][j] = __builtin_amdgcn_mfma_f32_16x16x32_bf16(af[i], bfr[j], acc[i][j], 0, 0, 0);
        __builtin_amdgcn_s_setprio(0);
    }
#undef STAGE_G

    float* C = (float*)Cv;
    unsigned short* Cb = (unsigned short*)Cv;
    #pragma unroll
    for (int i = 0; i < 4; i++) {
        int mbase = m0 + wm + i * 16 + quad * 4;
        #pragma unroll
        for (int j = 0; j < 4; j++) {
            int n = n0 + wn + j * 16 + l15;
            float bn = bias[j == 0 ? n : n];   // keep simple indexing
            #pragma unroll
            for (int r = 0; r < 4; r++) {
                size_t off = (size_t)(mbase + r) * 512 + n;
                float v = acc[i][j][r] + bn;
                if (RESID) v += resid[off];
                if (OUTBF) Cb[off] = f2b(v);
                else       C[off]  = v;
            }
        }
    }
}

// ---------------------------------------------------------------------------
// MFMA bf16 cross-attention v3: Q-projection FUSED.
// Each block computes its 64x64 Q-tile (abh-rows @ Wq-slice^T + bq) via a
// register-direct mini-GEMM (A and Wq fragments loaded straight from global,
// both L2-resident), bounces it through the PS2 LDS region (wave-local rows,
// within-wave write->read ordering) to convert C-layout -> A-fragment layout,
// then runs the proven QK^T / softmax / PV pipeline. Deletes the standalone
// Q-GEMM launch and the 67 MB qb round-trip.
// ---------------------------------------------------------------------------
#define KS2   0            // [80][72] bf16
#define VT2   5760         // [64][96] bf16, swizzled chunks
#define PS2   11904        // [64][104] bf16 (Q-tile bounce, then P)
#define SMEM2 18560        // ushorts = 37120 B

__global__ __launch_bounds__(256, 4) void attn_mfma3_kernel(
    const unsigned short* __restrict__ abh,
    const unsigned short* __restrict__ wqb,
    const float* __restrict__ bq,
    const unsigned short* __restrict__ kb,
    const unsigned short* __restrict__ vb,
    unsigned short* __restrict__ yout)
{
    __shared__ __align__(16) unsigned short smem[SMEM2];

    const int tid = threadIdx.x;
    const int t0 = blockIdx.x * 64;
    const int h  = blockIdx.y;
    const int b  = blockIdx.z;

    const int lane = tid & 63;
    const int w    = tid >> 6;
    const int l15  = lane & 15;
    const int quad = lane >> 4;
    const int koff = quad * 8;
    const int mrow = w * 16 + l15;

    // ---- stage K rows 0..79 (zero >=77): 640 bf16x8 tasks ----
    const unsigned short* kbase = kb + ((size_t)(b * N_)) * D_ + h * 64;
    #pragma unroll
    for (int i = 0; i < 3; i++) {
        int idx = tid + i * 256;
        if (idx < 640) {
            int row = idx >> 3, c8 = idx & 7;
            bf16x8 v = (bf16x8){0, 0, 0, 0, 0, 0, 0, 0};
            if (row < N_) v = *(const bf16x8*)(kbase + (size_t)row * D_ + c8 * 8);
            *(bf16x8*)&smem[KS2 + row * 72 + c8 * 8] = v;
        }
    }
    // ---- stage V transposed + swizzled: 616 bf16x8 tasks ----
    const unsigned short* vbase = vb + ((size_t)(b * N_)) * D_ + h * 64;
    #pragma unroll
    for (int i = 0; i < 3; i++) {
        int idx = tid + i * 256;
        if (idx < 616) {
            int n = idx >> 3, c8 = idx & 7;
            bf16x8 v = *(const bf16x8*)(vbase + (size_t)n * D_ + c8 * 8);
            int cn = n >> 3, wn = n & 7;
            #pragma unroll
            for (int j = 0; j < 8; j++) {
                int d = c8 * 8 + j;
                int s2 = (j ^ c8) & 3;                 // == (d ^ (d>>3)) & 3
                smem[VT2 + d * 96 + ((cn ^ s2) << 3) + wn] = v[j];
            }
        }
    }
    // ---- zero V pad: logical chunks 10,11 (vector) ----
    if (tid < 128) {
        int d = tid >> 1, c = 10 + (tid & 1);
        int s2 = (d ^ (d >> 3)) & 3;
        *(bf16x8*)&smem[VT2 + d * 96 + ((c ^ s2) << 3)] = (bf16x8){0, 0, 0, 0, 0, 0, 0, 0};
    }
    // ---- zero V pad: logical n = 77..79 (chunk 9, within 5..7) ----
    {
        int d = tid >> 2, t = tid & 3;
        if (t < 3) {
            int s2 = (d ^ (d >> 3)) & 3;
            smem[VT2 + d * 96 + ((9 ^ s2) << 3) + 5 + t] = 0;
        }
    }

    // ---- mini-GEMM: Q-tile = abh[t-rows] @ Wq[h-slice]^T (reg-direct) ----
    const unsigned short* arow = abh + ((size_t)(b * T_ + t0 + w * 16 + l15)) * D_;
    const unsigned short* wrow = wqb + ((size_t)(h * 64 + l15)) * D_;
    f32x4 qacc[4];
    #pragma unroll
    for (int j = 0; j < 4; j++) qacc[j] = (f32x4){0.f, 0.f, 0.f, 0.f};
    #pragma unroll 4
    for (int ks = 0; ks < 16; ks++) {
        bf16x8 af = *(const bf16x8*)(arow + ks * 32 + koff);
        #pragma unroll
        for (int j = 0; j < 4; j++) {
            bf16x8 wf = *(const bf16x8*)(wrow + (size_t)(j * 16) * D_ + ks * 32 + koff);
            qacc[j] = __builtin_amdgcn_mfma_f32_16x16x32_bf16(af, wf, qacc[j], 0, 0, 0);
        }
    }
    // ---- bounce Q-tile through PS2 (own rows; within-wave LDS ordering) ----
    #pragma unroll
    for (int j = 0; j < 4; j++) {
        float bn = bq[h * 64 + j * 16 + l15];
        #pragma unroll
        for (int r = 0; r < 4; r++) {
            smem[PS2 + (w * 16 + quad * 4 + r) * 104 + j * 16 + l15] =
                f2b(qacc[j][r] + bn);
        }
    }
    bf16x8 aq0 = *(const bf16x8*)&smem[PS2 + mrow * 104 + koff];
    bf16x8 aq1 = *(const bf16x8*)&smem[PS2 + mrow * 104 + 32 + koff];

    // ---- zero P pad cols 80..95 (cross-wave rows; covered by barrier) ----
    #pragma unroll
    for (int i = 0; i < 4; i++) {
        int idx = tid + i * 256;
        int row = idx >> 4, col = 80 + (idx & 15);
        smem[PS2 + row * 104 + col] = 0;
    }
    __syncthreads();

    // ---- QK^T ----
    float s[5][4];
    __builtin_amdgcn_s_setprio(1);
    #pragma unroll
    for (int nt = 0; nt < 5; nt++) {
        bf16x8 bk0 = *(const bf16x8*)&smem[KS2 + (nt * 16 + l15) * 72 + koff];
        bf16x8 bk1 = *(const bf16x8*)&smem[KS2 + (nt * 16 + l15) * 72 + 32 + koff];
        f32x4 c = {0.f, 0.f, 0.f, 0.f};
        c = __builtin_amdgcn_mfma_f32_16x16x32_bf16(aq0, bk0, c, 0, 0, 0);
        c = __builtin_amdgcn_mfma_f32_16x16x32_bf16(aq1, bk1, c, 0, 0, 0);
        #pragma unroll
        for (int r = 0; r < 4; r++) s[nt][r] = c[r];
    }
    __builtin_amdgcn_s_setprio(0);
    if (l15 >= N_ - 64) {
        #pragma unroll
        for (int r = 0; r < 4; r++) s[4][r] = -1e30f;
    }
    // ---- softmax over n ----
    float li[4];
    #pragma unroll
    for (int r = 0; r < 4; r++) {
        float m = s[0][r];
        #pragma unroll
        for (int nt = 1; nt < 5; nt++) m = fmaxf(m, s[nt][r]);
        m = fmaxf(m, __shfl_xor(m, 1));
        m = fmaxf(m, __shfl_xor(m, 2));
        m = fmaxf(m, __shfl_xor(m, 4));
        m = fmaxf(m, __shfl_xor(m, 8));
        float l = 0.f;
        #pragma unroll
        for (int nt = 0; nt < 5; nt++) {
            float ev = __expf(s[nt][r] - m);
            s[nt][r] = ev;
            l += ev;
        }
        l += __shfl_xor(l, 1);
        l += __shfl_xor(l, 2);
        l += __shfl_xor(l, 4);
        l += __shfl_xor(l, 8);
        li[r] = 1.f / l;
    }
    // P-store overwrites Q data in PS2 cols 0..79 — aq already in registers;
    // each wave touches only its own 16 rows (no cross-wave hazard).
    #pragma unroll
    for (int r = 0; r < 4; r++) {
        int prow = w * 16 + quad * 4 + r;
        #pragma unroll
        for (int nt = 0; nt < 5; nt++) {
            smem[PS2 + prow * 104 + nt * 16 + l15] = f2b(s[nt][r] * li[r]);
        }
    }
    // within-wave LDS write->read: per-wave LDS ordering + compiler lgkmcnt

    bf16x8 pa0 = *(const bf16x8*)&smem[PS2 + mrow * 104 + 0  + koff];
    bf16x8 pa1 = *(const bf16x8*)&smem[PS2 + mrow * 104 + 32 + koff];
    bf16x8 pa2 = *(const bf16x8*)&smem[PS2 + mrow * 104 + 64 + koff];

    unsigned short* obase = yout + ((size_t)(b * T_ + t0 + w * 16)) * D_ + h * 64;
    #pragma unroll
    for (int dt = 0; dt < 4; dt++) {
        int drow = dt * 16 + l15;
        int s2 = (drow ^ (drow >> 3)) & 3;
        bf16x8 bv0 = *(const bf16x8*)&smem[VT2 + drow * 96 + (((0 + quad) ^ s2) << 3)];
        bf16x8 bv1 = *(const bf16x8*)&smem[VT2 + drow * 96 + (((4 + quad) ^ s2) << 3)];
        bf16x8 bv2 = *(const bf16x8*)&smem[VT2 + drow * 96 + (((8 + quad) ^ s2) << 3)];
        f32x4 c = {0.f, 0.f, 0.f, 0.f};
        __builtin_amdgcn_s_setprio(1);
        c = __builtin_amdgcn_mfma_f32_16x16x32_bf16(pa0, bv0, c, 0, 0, 0);
        c = __builtin_amdgcn_mfma_f32_16x16x32_bf16(pa1, bv1, c, 0, 0, 0);
        c = __builtin_amdgcn_mfma_f32_16x16x32_bf16(pa2, bv2, c, 0, 0, 0);
        __builtin_amdgcn_s_setprio(0);
        #pragma unroll
        for (int r = 0; r < 4; r++) {
            obase[(size_t)(quad * 4 + r) * D_ + dt * 16 + l15] = f2b(c[r]);
        }
    }
}

// ---------------------------------------------------------------------------
extern "C" void kernel_launch(void* const* d_in, const int* in_sizes, int n_in,
                              void* d_out, int out_size, void* d_ws, size_t ws_size,
                              hipStream_t stream)
{
    const float* x       = (const float*)d_in[0];
    const float* xf      = (const float*)d_in[1];
    const float* emb     = (const float*)d_in[2];
    const int*   cond    = (const int*)d_in[4];
    const float* norm_w  = (const float*)d_in[5];
    const float* norm_b  = (const float*)d_in[6];
    const float* tnorm_w = (const float*)d_in[7];
    const float* tnorm_b = (const float*)d_in[8];
    const float* Wq      = (const float*)d_in[9];
    const float* bq      = (const float*)d_in[10];
    const float* Wk      = (const float*)d_in[11];
    const float* bk      = (const float*)d_in[12];
    const float* Wv      = (const float*)d_in[13];
    const float* bv      = (const float*)d_in[14];
    const float* emb_w   = (const float*)d_in[15];
    const float* emb_b   = (const float*)d_in[16];
    const float* snorm_w = (const float*)d_in[17];
    const float* snorm_b = (const float*)d_in[18];
    const float* Wout    = (const float*)d_in[19];
    const float* bout    = (const float*)d_in[20];
    float* out = (float*)d_out;

    float* ws = (float*)d_ws;
    float* ebuf = ws;                                  // 32*1024 f32
    unsigned short* u = (unsigned short*)(ebuf + (size_t)B_ * 2 * D_);
    unsigned short* qyb  = u;  u += (size_t)B_ * T_ * D_;      // y bf16 (attn out)
    unsigned short* xfnb = u;  u += (size_t)2560 * TD_;        // LN(xf) bf16, padded rows
    unsigned short* kb16 = u;  u += (size_t)B_ * N_ * D_;      // K bf16
    unsigned short* vb16 = u;  u += (size_t)B_ * N_ * D_;      // V bf16 (gated)
    unsigned short* abh  = u;  u += (size_t)B_ * T_ * D_;      // bf16 LN(x)
    unsigned short* wqb  = u;  u += (size_t)D_ * D_;
    unsigned short* wob  = u;  u += (size_t)D_ * D_;
    unsigned short* wkvb = u;  u += (size_t)2 * D_ * TD_;      // [Wk;Wv] bf16

    const int BT = B_ * T_;      // 32768
    const int BN = B_ * N_;      // 2464

    // 1. xf layernorm -> bf16
    ln_xf_kernel<<<BN / 4, 256, 0, stream>>>(xf, tnorm_w, tnorm_b, xfnb);
    // 2. all weight converts in one launch
    conv_weights_kernel<<<384, 256, 0, stream>>>(Wq, Wout, Wk, Wv, wqb, wob, wkvb);
    // 3. fused K+V projection (bf16 MFMA, bf16 out, V gated)
    kv_gemm_kernel<<<160, 256, 0, stream>>>(xfnb, wkvb, bk, bv, cond, kb16, vb16);
    // 4. prep A: abh = bf16(LN(x))
    prep_q_kernel<<<BT / 4, 256, 0, stream>>>(x, norm_w, norm_b, abh);
    // 5. emb path: ebuf = silu(emb) @ emb_w^T (silu fused; bias folded into prep_h)
    emb_gemm_kernel<<<512, 256, 0, stream>>>(emb, emb_w, ebuf);
    // 6. attention with fused Q-projection: abh/wqb/bq + kb16/vb16 -> y (bf16)
    {
        dim3 grid(T_ / 64, H_, B_);
        attn_mfma3_kernel<<<grid, 256, 0, stream>>>(abh, wqb, bq, kb16, vb16, qyb);
    }
    // 7. prep A for out-GEMM: abh = bf16(silu(LN(y)*(1+sc)+sh))
    prep_h_kernel<<<BT / 4, 256, 0, stream>>>(qyb, snorm_w, snorm_b, ebuf, emb_b, abh);
    // 8. out projection (bf16 MFMA, fp32 out + residual): out = abh @ wob^T + bout + x
    gemm_bf16_kernel<1, 0><<<1024, 256, 0, stream>>>(abh, wob, bout, x, out);
}

// Round 9
// 294.107 us; speedup vs baseline: 1.3439x; 1.3439x over previous
//
#include <hip/hip_runtime.h>
#include <math.h>

#define B_   32
#define T_   1024
#define N_   77
#define D_   512
#define TD_  256
#define TE_  2048
#define H_   8
#define DH_  64

typedef short bf16x8 __attribute__((ext_vector_type(8)));
typedef float f32x4  __attribute__((ext_vector_type(4)));

__device__ __forceinline__ float sigmoidf_fast(float x) {
    return 1.0f / (1.0f + __expf(-x));
}

// float -> bf16 bits, round-to-nearest-even
__device__ __forceinline__ unsigned short f2b(float f) {
    unsigned int u = __float_as_uint(f);
    unsigned int r = u + 0x7FFFu + ((u >> 16) & 1u);
    return (unsigned short)(r >> 16);
}

// bf16 bits -> float
__device__ __forceinline__ float b2f(short us) {
    return __uint_as_float(((unsigned int)(unsigned short)us) << 16);
}

// async global->LDS 16B (wave-uniform LDS base + lane*16 required)
#define GL16(g, l) __builtin_amdgcn_global_load_lds(                         \
    (const __attribute__((address_space(1))) unsigned int*)(g),              \
    (__attribute__((address_space(3))) unsigned int*)(l), 16, 0, 0)

#define WAITV8()  asm volatile("s_waitcnt vmcnt(8)"  ::: "memory")
#define WAITV4()  asm volatile("s_waitcnt vmcnt(4)"  ::: "memory")
#define WAITV0()  asm volatile("s_waitcnt vmcnt(0)"  ::: "memory")
#define WAITL0()  asm volatile("s_waitcnt lgkmcnt(0)" ::: "memory")
#define SBAR()   __builtin_amdgcn_s_barrier()
#define SCHED0() __builtin_amdgcn_sched_barrier(0)

// ===========================================================================
// Prelude bodies (all independent; merged into ONE launch)
// ===========================================================================

// prep_q: abh = bf16(LN(x; norm_w, norm_b)). One wave per 512-row.
__device__ __forceinline__ void prep_q_body(
    int bid, int tid,
    const float* __restrict__ x, const float* __restrict__ w, const float* __restrict__ b,
    unsigned short* __restrict__ outb)
{
    int row = bid * 4 + (tid >> 6);
    int lane = tid & 63;
    const float* rp = x + (size_t)row * D_ + lane * 8;
    float4 v0 = *(const float4*)rp;
    float4 v1 = *(const float4*)(rp + 4);
    float s  = v0.x + v0.y + v0.z + v0.w + v1.x + v1.y + v1.z + v1.w;
    float ss = v0.x*v0.x + v0.y*v0.y + v0.z*v0.z + v0.w*v0.w
             + v1.x*v1.x + v1.y*v1.y + v1.z*v1.z + v1.w*v1.w;
    #pragma unroll
    for (int off = 32; off; off >>= 1) {
        s  += __shfl_xor(s, off);
        ss += __shfl_xor(ss, off);
    }
    float m = s * (1.f / D_);
    float r = rsqrtf(ss * (1.f / D_) - m * m + 1e-5f);
    float4 w0 = *(const float4*)(w + lane * 8);
    float4 w1 = *(const float4*)(w + lane * 8 + 4);
    float4 b0 = *(const float4*)(b + lane * 8);
    float4 b1 = *(const float4*)(b + lane * 8 + 4);
    ushort4 o0, o1;
    o0.x = f2b((v0.x - m) * r * w0.x + b0.x);
    o0.y = f2b((v0.y - m) * r * w0.y + b0.y);
    o0.z = f2b((v0.z - m) * r * w0.z + b0.z);
    o0.w = f2b((v0.w - m) * r * w0.w + b0.w);
    o1.x = f2b((v1.x - m) * r * w1.x + b1.x);
    o1.y = f2b((v1.y - m) * r * w1.y + b1.y);
    o1.z = f2b((v1.z - m) * r * w1.z + b1.z);
    o1.w = f2b((v1.w - m) * r * w1.w + b1.w);
    unsigned short* op = outb + (size_t)row * D_ + lane * 8;
    *(ushort4*)op       = o0;
    *(ushort4*)(op + 4) = o1;
}

// xf layernorm -> bf16. One wave per 256-col row.
__device__ __forceinline__ void ln_xf_body(
    int bid, int tid,
    const float* __restrict__ x, const float* __restrict__ w, const float* __restrict__ b,
    unsigned short* __restrict__ outb)
{
    int row = bid * 4 + (tid >> 6);
    int lane = tid & 63;
    const float* rp = x + (size_t)row * TD_ + lane * 4;
    float4 v = *(const float4*)rp;
    float s  = v.x + v.y + v.z + v.w;
    float ss = v.x*v.x + v.y*v.y + v.z*v.z + v.w*v.w;
    #pragma unroll
    for (int off = 32; off; off >>= 1) {
        s  += __shfl_xor(s, off);
        ss += __shfl_xor(ss, off);
    }
    float m = s * (1.f / TD_);
    float r = rsqrtf(ss * (1.f / TD_) - m * m + 1e-5f);
    float4 wv = *(const float4*)(w + lane * 4);
    float4 bv = *(const float4*)(b + lane * 4);
    ushort4 o;
    o.x = f2b((v.x - m) * r * wv.x + bv.x);
    o.y = f2b((v.y - m) * r * wv.y + bv.y);
    o.z = f2b((v.z - m) * r * wv.z + bv.z);
    o.w = f2b((v.w - m) * r * wv.w + bv.w);
    *(ushort4*)(outb + (size_t)row * TD_ + lane * 4) = o;
}

// weight fp32->bf16 converts.
__device__ __forceinline__ void conv_weights_body(
    int bid, int tid,
    const float* __restrict__ Wq, const float* __restrict__ Wout,
    const float* __restrict__ Wk, const float* __restrict__ Wv,
    unsigned short* __restrict__ wqb, unsigned short* __restrict__ wob,
    unsigned short* __restrict__ wkvb)
{
    const float* src; unsigned short* dst;
    if (bid < 128)      { src = Wq;   dst = wqb; }
    else if (bid < 256) { src = Wout; dst = wob;               bid -= 128; }
    else if (bid < 320) { src = Wk;   dst = wkvb;              bid -= 256; }
    else                { src = Wv;   dst = wkvb + D_ * TD_;   bid -= 320; }
    int idx = (bid * 256 + tid) * 8;
    float4 v0 = *(const float4*)(src + idx);
    float4 v1 = *(const float4*)(src + idx + 4);
    ushort4 o0 = {f2b(v0.x), f2b(v0.y), f2b(v0.z), f2b(v0.w)};
    ushort4 o1 = {f2b(v1.x), f2b(v1.y), f2b(v1.z), f2b(v1.w)};
    *(ushort4*)(dst + idx)     = o0;
    *(ushort4*)(dst + idx + 4) = o1;
}

// emb GEMM with fused silu: e[32][1024] = silu(emb)[32][2048] @ emb_w^T.
__device__ __forceinline__ void emb_gemm_body(
    int bid, int tid,
    const float* __restrict__ emb, const float* __restrict__ W,
    float* __restrict__ e)
{
    int wid = bid * 4 + (tid >> 6);   // 0..2047
    int lane = tid & 63;
    int ngrp = wid >> 3;        // 0..255  (4 n each)
    int bgrp = wid & 7;         // 0..7    (4 b each)

    float acc[4][4] = {};
    #pragma unroll 2
    for (int it = 0; it < 8; it++) {
        int k = (it * 64 + lane) * 4;
        float4 sv[4], wv[4];
        #pragma unroll
        for (int bi = 0; bi < 4; bi++) {
            float4 t = *(const float4*)&emb[(size_t)(bgrp * 4 + bi) * TE_ + k];
            t.x *= sigmoidf_fast(t.x);
            t.y *= sigmoidf_fast(t.y);
            t.z *= sigmoidf_fast(t.z);
            t.w *= sigmoidf_fast(t.w);
            sv[bi] = t;
        }
        #pragma unroll
        for (int ni = 0; ni < 4; ni++)
            wv[ni] = *(const float4*)&W[(size_t)(ngrp * 4 + ni) * TE_ + k];
        #pragma unroll
        for (int bi = 0; bi < 4; bi++)
            #pragma unroll
            for (int ni = 0; ni < 4; ni++) {
                acc[bi][ni] = fmaf(sv[bi].x, wv[ni].x, acc[bi][ni]);
                acc[bi][ni] = fmaf(sv[bi].y, wv[ni].y, acc[bi][ni]);
                acc[bi][ni] = fmaf(sv[bi].z, wv[ni].z, acc[bi][ni]);
                acc[bi][ni] = fmaf(sv[bi].w, wv[ni].w, acc[bi][ni]);
            }
    }
    #pragma unroll
    for (int bi = 0; bi < 4; bi++)
        #pragma unroll
        for (int ni = 0; ni < 4; ni++) {
            float a = acc[bi][ni];
            #pragma unroll
            for (int off = 32; off; off >>= 1) a += __shfl_xor(a, off);
            if (lane == 0)
                e[(size_t)(bgrp * 4 + bi) * 1024 + ngrp * 4 + ni] = a;
        }
}

// Merged prelude launch: [0,8192) prep_q | [8192,8808) ln_xf |
// [8808,9192) conv_weights | [9192,9704) emb_gemm.
__global__ __launch_bounds__(256) void prelude_kernel(
    const float* __restrict__ x, const float* __restrict__ norm_w, const float* __restrict__ norm_b,
    unsigned short* __restrict__ abh,
    const float* __restrict__ xf, const float* __restrict__ tnorm_w, const float* __restrict__ tnorm_b,
    unsigned short* __restrict__ xfnb,
    const float* __restrict__ Wq, const float* __restrict__ Wout,
    const float* __restrict__ Wk, const float* __restrict__ Wv,
    unsigned short* __restrict__ wqb, unsigned short* __restrict__ wob,
    unsigned short* __restrict__ wkvb,
    const float* __restrict__ emb, const float* __restrict__ emb_w,
    float* __restrict__ ebuf)
{
    int bid = blockIdx.x;
    int tid = threadIdx.x;
    if (bid < 8192)      prep_q_body(bid, tid, x, norm_w, norm_b, abh);
    else if (bid < 8808) ln_xf_body(bid - 8192, tid, xf, tnorm_w, tnorm_b, xfnb);
    else if (bid < 9192) conv_weights_body(bid - 8808, tid, Wq, Wout, Wk, Wv, wqb, wob, wkvb);
    else                 emb_gemm_body(bid - 9192, tid, emb, emb_w, ebuf);
}

// ===========================================================================
// Projection bodies (Q-GEMM + KV-GEMM; merged into ONE launch, shared LDS)
// smem layout (ushorts): As = [0, 12288) (3 bufs x 4096), Bs = [12288, 24576)
// ===========================================================================

// Q projection: qb = bf16(abh @ wqb^T + bq). Round-4 counted-vmcnt pipeline.
__device__ __forceinline__ void qgemm_body(
    int id, int tid, unsigned short* smem,
    const unsigned short* __restrict__ Ab,
    const unsigned short* __restrict__ Wb,
    const float* __restrict__ bias,
    unsigned short* __restrict__ Cb)
{
    constexpr int K = 512;
    constexpr int NSTEP = 16;
    int swz = (id & 7) * 128 + (id >> 3);
    const int m0 = (swz >> 2) * 128;
    const int n0 = (swz & 3) * 128;
    const int lane = tid & 63;
    const int w    = tid >> 6;
    const int l15  = lane & 15;
    const int quad = lane >> 4;
    const int wm   = (w >> 1) * 64;
    const int wn   = (w & 1) * 64;

    const int row_s = tid >> 2;
    const int ck    = (tid & 3) ^ ((row_s >> 1) & 3);
    const int sc    = (quad ^ ((l15 >> 1) & 3)) << 3;

    f32x4 acc[4][4];
    #pragma unroll
    for (int i = 0; i < 4; i++)
        #pragma unroll
        for (int j = 0; j < 4; j++)
            acc[i][j] = (f32x4){0.f, 0.f, 0.f, 0.f};

    const char* gA = (const char*)Ab + ((size_t)(m0 + row_s) * K) * 2 + ck * 16;
    const char* gB = (const char*)Wb + ((size_t)(n0 + row_s) * K) * 2 + ck * 16;
    const size_t g2 = (size_t)64 * K * 2;
    char* lA = (char*)smem + tid * 16;
    char* lB = (char*)smem + 24576 + tid * 16;

#define STAGE_Q(s, buf) do {                                                  \
        GL16(gA + (s) * 64,      lA + (buf) * 8192);                          \
        GL16(gA + (s) * 64 + g2, lA + (buf) * 8192 + 4096);                   \
        GL16(gB + (s) * 64,      lB + (buf) * 8192);                          \
        GL16(gB + (s) * 64 + g2, lB + (buf) * 8192 + 4096);                   \
    } while (0)

    STAGE_Q(0, 0);
    STAGE_Q(1, 1);
    STAGE_Q(2, 2);

    bf16x8 af[4], bfr[4];
    #pragma unroll
    for (int t = 0; t < NSTEP; t++) {
        const int cur = t % 3;
        if (t < NSTEP - 2)       { WAITV8(); }
        else if (t == NSTEP - 2) { WAITV4(); }
        else                     { WAITV0(); }
        SBAR(); SCHED0();
        #pragma unroll
        for (int i = 0; i < 4; i++)
            af[i] = *(const bf16x8*)&smem[cur * 4096 + (wm + i * 16 + l15) * 32 + sc];
        #pragma unroll
        for (int j = 0; j < 4; j++)
            bfr[j] = *(const bf16x8*)&smem[12288 + cur * 4096 + (wn + j * 16 + l15) * 32 + sc];
        WAITL0(); SCHED0();
        SBAR(); SCHED0();
        if (t + 3 < NSTEP) STAGE_Q(t + 3, cur);
        __builtin_amdgcn_s_setprio(1);
        #pragma unroll
        for (int i = 0; i < 4; i++)
            #pragma unroll
            for (int j = 0; j < 4; j++)
                acc[i][j] = __builtin_amdgcn_mfma_f32_16x16x32_bf16(af[i], bfr[j], acc[i][j], 0, 0, 0);
        __builtin_amdgcn_s_setprio(0);
    }
#undef STAGE_Q

    #pragma unroll
    for (int i = 0; i < 4; i++) {
        int mbase = m0 + wm + i * 16 + quad * 4;
        #pragma unroll
        for (int j = 0; j < 4; j++) {
            int n = n0 + wn + j * 16 + l15;
            float bn = bias[n];
            #pragma unroll
            for (int r = 0; r < 4; r++) {
                size_t off = (size_t)(mbase + r) * 512 + n;
                Cb[off] = f2b(acc[i][j][r] + bn);
            }
        }
    }
}

// Fused K+V projection (K=256), round-4 counted-vmcnt pipeline.
__device__ __forceinline__ void kv_body(
    int id, int tid, unsigned short* smem,
    const unsigned short* __restrict__ Ab,
    const unsigned short* __restrict__ Wb,
    const float* __restrict__ bkp, const float* __restrict__ bvp,
    const int*   __restrict__ cond,
    unsigned short* __restrict__ kout, unsigned short* __restrict__ vout)
{
    constexpr int K = TD_;       // 256
    constexpr int NSTEP = 8;
    int swz = (id & 7) * 20 + (id >> 3);
    const int m0 = (swz >> 3) * 128;
    const int n0 = (swz & 7) * 128;
    const int lane = tid & 63;
    const int w    = tid >> 6;
    const int l15  = lane & 15;
    const int quad = lane >> 4;
    const int wm   = (w >> 1) * 64;
    const int wn   = (w & 1) * 64;

    const int row_a = tid >> 2;
    const int ck    = (tid & 3) ^ ((row_a >> 1) & 3);
    const int sc    = (quad ^ ((l15 >> 1) & 3)) << 3;

    f32x4 acc[4][4];
    #pragma unroll
    for (int i = 0; i < 4; i++)
        #pragma unroll
        for (int j = 0; j < 4; j++)
            acc[i][j] = (f32x4){0.f, 0.f, 0.f, 0.f};

    const char* gA = (const char*)Ab + ((size_t)(m0 + row_a) * K) * 2 + ck * 16;
    const char* gB = (const char*)Wb + ((size_t)(n0 + row_a) * K) * 2 + ck * 16;
    const size_t g2 = (size_t)64 * K * 2;
    char* lA = (char*)smem + tid * 16;
    char* lB = (char*)smem + 24576 + tid * 16;

#define KSTAGE(s, buf) do {                                                   \
        GL16(gA + (s) * 64,      lA + (buf) * 8192);                          \
        GL16(gA + (s) * 64 + g2, lA + (buf) * 8192 + 4096);                   \
        GL16(gB + (s) * 64,      lB + (buf) * 8192);                          \
        GL16(gB + (s) * 64 + g2, lB + (buf) * 8192 + 4096);                   \
    } while (0)

    KSTAGE(0, 0);
    KSTAGE(1, 1);
    KSTAGE(2, 2);

    bf16x8 af[4], bfr[4];
    #pragma unroll
    for (int t = 0; t < NSTEP; t++) {
        const int cur = t % 3;
        if (t < NSTEP - 2)       { WAITV8(); }
        else if (t == NSTEP - 2) { WAITV4(); }
        else                     { WAITV0(); }
        SBAR(); SCHED0();
        #pragma unroll
        for (int i = 0; i < 4; i++)
            af[i] = *(const bf16x8*)&smem[cur * 4096 + (wm + i * 16 + l15) * 32 + sc];
        #pragma unroll
        for (int j = 0; j < 4; j++)
            bfr[j] = *(const bf16x8*)&smem[12288 + cur * 4096 + (wn + j * 16 + l15) * 32 + sc];
        WAITL0(); SCHED0();
        SBAR(); SCHED0();
        if (t + 3 < NSTEP) KSTAGE(t + 3, cur);
        __builtin_amdgcn_s_setprio(1);
        #pragma unroll
        for (int i = 0; i < 4; i++)
            #pragma unroll
            for (int j = 0; j < 4; j++)
                acc[i][j] = __builtin_amdgcn_mfma_f32_16x16x32_bf16(af[i], bfr[j], acc[i][j], 0, 0, 0);
        __builtin_amdgcn_s_setprio(0);
    }
#undef KSTAGE

    #pragma unroll
    for (int i = 0; i < 4; i++) {
        int mbase = m0 + wm + i * 16 + quad * 4;
        #pragma unroll
        for (int j = 0; j < 4; j++) {
            int n = n0 + wn + j * 16 + l15;
            bool isv = n >= D_;
            int nn = isv ? n - D_ : n;
            float bn = isv ? bvp[nn] : bkp[nn];
            unsigned short* outp = isv ? vout : kout;
            #pragma unroll
            for (int r = 0; r < 4; r++) {
                int m = mbase + r;
                if (m >= B_ * N_) continue;
                float v = acc[i][j][r] + bn;
                if (isv) {
                    int bi = m / N_;
                    v = ((cond[bi] % 10) > 0) ? v : 0.f;
                }
                outp[(size_t)m * D_ + nn] = f2b(v);
            }
        }
    }
}

// Merged projection launch: [0,1024) Q-GEMM | [1024,1184) KV-GEMM.
__global__ __launch_bounds__(256) void proj_kernel(
    const unsigned short* __restrict__ abh,
    const unsigned short* __restrict__ wqb,
    const float* __restrict__ bq,
    unsigned short* __restrict__ qb,
    const unsigned short* __restrict__ xfnb,
    const unsigned short* __restrict__ wkvb,
    const float* __restrict__ bk, const float* __restrict__ bv,
    const int* __restrict__ cond,
    unsigned short* __restrict__ kb16, unsigned short* __restrict__ vb16)
{
    __shared__ __align__(16) unsigned short smem[24576];   // 48 KB shared by both paths
    int bid = blockIdx.x;
    int tid = threadIdx.x;
    if (bid < 1024) qgemm_body(bid, tid, smem, abh, wqb, bq, qb);
    else            kv_body(bid - 1024, tid, smem, xfnb, wkvb, bk, bv, cond, kb16, vb16);
}

// ---------------------------------------------------------------------------
// prep_h: out_bf16 = bf16( silu( LN(y)*(1+sc) + sh ) ), sc/sh = e + emb_b.
// ---------------------------------------------------------------------------
__global__ __launch_bounds__(256) void prep_h_kernel(
    const unsigned short* __restrict__ y, const float* __restrict__ w, const float* __restrict__ b,
    const float* __restrict__ e, const float* __restrict__ emb_b,
    unsigned short* __restrict__ outb)
{
    int row = blockIdx.x * 4 + (threadIdx.x >> 6);
    int lane = threadIdx.x & 63;
    int bb = row >> 10;
    const unsigned short* rp = y + (size_t)row * D_ + lane * 8;
    bf16x8 yv = *(const bf16x8*)rp;
    float v[8];
    #pragma unroll
    for (int k2 = 0; k2 < 8; k2++) v[k2] = b2f(yv[k2]);
    float s = 0.f, ss = 0.f;
    #pragma unroll
    for (int k2 = 0; k2 < 8; k2++) { s += v[k2]; ss += v[k2] * v[k2]; }
    #pragma unroll
    for (int off = 32; off; off >>= 1) {
        s  += __shfl_xor(s, off);
        ss += __shfl_xor(ss, off);
    }
    float m = s * (1.f / D_);
    float r = rsqrtf(ss * (1.f / D_) - m * m + 1e-5f);
    float4 w0 = *(const float4*)(w + lane * 8);
    float4 w1 = *(const float4*)(w + lane * 8 + 4);
    float4 b0 = *(const float4*)(b + lane * 8);
    float4 b1 = *(const float4*)(b + lane * 8 + 4);
    float wa[8] = {w0.x, w0.y, w0.z, w0.w, w1.x, w1.y, w1.z, w1.w};
    float ba[8] = {b0.x, b0.y, b0.z, b0.w, b1.x, b1.y, b1.z, b1.w};
    const float* ep = e + (size_t)bb * 1024 + lane * 8;
    float4 sc0 = *(const float4*)ep;
    float4 sc1 = *(const float4*)(ep + 4);
    float4 sh0 = *(const float4*)(ep + 512);
    float4 sh1 = *(const float4*)(ep + 512 + 4);
    float4 eb0 = *(const float4*)(emb_b + lane * 8);
    float4 eb1 = *(const float4*)(emb_b + lane * 8 + 4);
    float4 fb0 = *(const float4*)(emb_b + 512 + lane * 8);
    float4 fb1 = *(const float4*)(emb_b + 512 + lane * 8 + 4);
    float sca[8] = {sc0.x + eb0.x, sc0.y + eb0.y, sc0.z + eb0.z, sc0.w + eb0.w,
                    sc1.x + eb1.x, sc1.y + eb1.y, sc1.z + eb1.z, sc1.w + eb1.w};
    float sha[8] = {sh0.x + fb0.x, sh0.y + fb0.y, sh0.z + fb0.z, sh0.w + fb0.w,
                    sh1.x + fb1.x, sh1.y + fb1.y, sh1.z + fb1.z, sh1.w + fb1.w};
    ushort4 o0, o1;
    unsigned short oa[8];
    #pragma unroll
    for (int k2 = 0; k2 < 8; k2++) {
        float hv = ((v[k2] - m) * r * wa[k2] + ba[k2]) * (1.f + sca[k2]) + sha[k2];
        oa[k2] = f2b(hv * sigmoidf_fast(hv));
    }
    o0.x = oa[0]; o0.y = oa[1]; o0.z = oa[2]; o0.w = oa[3];
    o1.x = oa[4]; o1.y = oa[5]; o1.z = oa[6]; o1.w = oa[7];
    unsigned short* op = outb + (size_t)row * D_ + lane * 8;
    *(ushort4*)op       = o0;
    *(ushort4*)(op + 4) = o1;
}

// ---------------------------------------------------------------------------
// bf16 MFMA GEMM (round-4 structure): 128x128 tile, BK=32, 3-buffer LDS,
// counted-vmcnt pipeline, chunk-XOR LDS swizzle, XCD-chunked block swizzle.
// Used standalone for the out-projection (RESID=1, fp32 out).
// ---------------------------------------------------------------------------
template <int RESID, int OUTBF>
__global__ __launch_bounds__(256) void gemm_bf16_kernel(
    const unsigned short* __restrict__ Ab,
    const unsigned short* __restrict__ Wb,
    const float* __restrict__ bias,
    const float* __restrict__ resid,
    void* __restrict__ Cv)
{
    constexpr int K = 512;
    constexpr int NSTEP = 16;    // K / 32
    __shared__ __align__(16) unsigned short As[3][128 * 32];
    __shared__ __align__(16) unsigned short Bs[3][128 * 32];

    const int tid  = threadIdx.x;
    int id = blockIdx.x;
    int swz = (id & 7) * 128 + (id >> 3);
    const int m0 = (swz >> 2) * 128;
    const int n0 = (swz & 3) * 128;
    const int lane = tid & 63;
    const int w    = tid >> 6;
    const int l15  = lane & 15;
    const int quad = lane >> 4;
    const int wm   = (w >> 1) * 64;
    const int wn   = (w & 1) * 64;

    const int row_s = tid >> 2;
    const int ck    = (tid & 3) ^ ((row_s >> 1) & 3);
    const int sc    = (quad ^ ((l15 >> 1) & 3)) << 3;

    f32x4 acc[4][4];
    #pragma unroll
    for (int i = 0; i < 4; i++)
        #pragma unroll
        for (int j = 0; j < 4; j++)
            acc[i][j] = (f32x4){0.f, 0.f, 0.f, 0.f};

    const char* gA = (const char*)Ab + ((size_t)(m0 + row_s) * K) * 2 + ck * 16;
    const char* gB = (const char*)Wb + ((size_t)(n0 + row_s) * K) * 2 + ck * 16;
    const size_t g2 = (size_t)64 * K * 2;
    char* lA = (char*)&As[0][0] + tid * 16;
    char* lB = (char*)&Bs[0][0] + tid * 16;

#define STAGE_G(s, buf) do {                                                  \
        GL16(gA + (s) * 64,      lA + (buf) * 8192);                          \
        GL16(gA + (s) * 64 + g2, lA + (buf) * 8192 + 4096);                   \
        GL16(gB + (s) * 64,      lB + (buf) * 8192);                          \
        GL16(gB + (s) * 64 + g2, lB + (buf) * 8192 + 4096);                   \
    } while (0)

    STAGE_G(0, 0);
    STAGE_G(1, 1);
    STAGE_G(2, 2);

    bf16x8 af[4], bfr[4];
    #pragma unroll
    for (int t = 0; t < NSTEP; t++) {
        const int cur = t % 3;
        if (t < NSTEP - 2)       { WAITV8(); }
        else if (t == NSTEP - 2) { WAITV4(); }
        else                     { WAITV0(); }
        SBAR(); SCHED0();
        #pragma unroll
        for (int i = 0; i < 4; i++)
            af[i] = *(const bf16x8*)&As[cur][(wm + i * 16 + l15) * 32 + sc];
        #pragma unroll
        for (int j = 0; j < 4; j++)
            bfr[j] = *(const bf16x8*)&Bs[cur][(wn + j * 16 + l15) * 32 + sc];
        WAITL0(); SCHED0();
        SBAR(); SCHED0();
        if (t + 3 < NSTEP) STAGE_G(t + 3, cur);
        __builtin_amdgcn_s_setprio(1);
        #pragma unroll
        for (int i = 0; i < 4; i++)
            #pragma unroll
            for (int j = 0; j < 4; j++)
                acc[i][j] = __builtin_amdgcn_mfma_f32_16x16x32_bf16(af[i], bfr[j], acc[i][j], 0, 0, 0);
        __builtin_amdgcn_s_setprio(0);
    }
#undef STAGE_G

    float* C = (float*)Cv;
    unsigned short* Cb = (unsigned short*)Cv;
    #pragma unroll
    for (int i = 0; i < 4; i++) {
        int mbase = m0 + wm + i * 16 + quad * 4;
        #pragma unroll
        for (int j = 0; j < 4; j++) {
            int n = n0 + wn + j * 16 + l15;
            float bn = bias[n];
            #pragma unroll
            for (int r = 0; r < 4; r++) {
                size_t off = (size_t)(mbase + r) * 512 + n;
                float v = acc[i][j][r] + bn;
                if (RESID) v += resid[off];
                if (OUTBF) Cb[off] = f2b(v);
                else       C[off]  = v;
            }
        }
    }
}

// ---------------------------------------------------------------------------
// MFMA bf16 cross-attention v2 (bf16 y output) — round-4 version.
// ---------------------------------------------------------------------------
#define KS2   0            // [80][72] bf16
#define VT2   5760         // [64][96] bf16, swizzled chunks
#define PS2   11904        // [64][104] bf16
#define SMEM2 18560        // ushorts = 37120 B

__global__ __launch_bounds__(256) void attn_mfma2_kernel(
    const unsigned short* __restrict__ qb,
    const unsigned short* __restrict__ kb,
    const unsigned short* __restrict__ vb,
    unsigned short* __restrict__ yout)
{
    __shared__ __align__(16) unsigned short smem[SMEM2];

    const int tid = threadIdx.x;
    const int t0 = blockIdx.x * 64;
    const int h  = blockIdx.y;
    const int b  = blockIdx.z;

    const int lane = tid & 63;
    const int w    = tid >> 6;
    const int l15  = lane & 15;
    const int quad = lane >> 4;
    const int koff = quad * 8;
    const int mrow = w * 16 + l15;

    // ---- issue Q fragment loads early (global, read-once) ----
    const unsigned short* qrow = qb + ((size_t)(b * T_ + t0 + mrow)) * D_ + h * 64 + koff;
    bf16x8 aq0 = *(const bf16x8*)qrow;
    bf16x8 aq1 = *(const bf16x8*)(qrow + 32);

    // ---- stage K rows 0..79 (zero >=77): 640 bf16x8 tasks ----
    const unsigned short* kbase = kb + ((size_t)(b * N_)) * D_ + h * 64;
    #pragma unroll
    for (int i = 0; i < 3; i++) {
        int idx = tid + i * 256;
        if (idx < 640) {
            int row = idx >> 3, c8 = idx & 7;
            bf16x8 v = (bf16x8){0, 0, 0, 0, 0, 0, 0, 0};
            if (row < N_) v = *(const bf16x8*)(kbase + (size_t)row * D_ + c8 * 8);
            *(bf16x8*)&smem[KS2 + row * 72 + c8 * 8] = v;
        }
    }
    // ---- stage V transposed + swizzled: 616 bf16x8 tasks ----
    const unsigned short* vbase = vb + ((size_t)(b * N_)) * D_ + h * 64;
    #pragma unroll
    for (int i = 0; i < 3; i++) {
        int idx = tid + i * 256;
        if (idx < 616) {
            int n = idx >> 3, c8 = idx & 7;
            bf16x8 v = *(const bf16x8*)(vbase + (size_t)n * D_ + c8 * 8);
            int cn = n >> 3, wn = n & 7;
            #pragma unroll
            for (int j = 0; j < 8; j++) {
                int d = c8 * 8 + j;
                int s2 = (j ^ c8) & 3;                 // == (d ^ (d>>3)) & 3
                smem[VT2 + d * 96 + ((cn ^ s2) << 3) + wn] = v[j];
            }
        }
    }
    // ---- zero V pad: logical chunks 10,11 (vector) ----
    if (tid < 128) {
        int d = tid >> 1, c = 10 + (tid & 1);
        int s2 = (d ^ (d >> 3)) & 3;
        *(bf16x8*)&smem[VT2 + d * 96 + ((c ^ s2) << 3)] = (bf16x8){0, 0, 0, 0, 0, 0, 0, 0};
    }
    // ---- zero V pad: logical n = 77..79 (chunk 9, within 5..7) ----
    {
        int d = tid >> 2, t = tid & 3;
        if (t < 3) {
            int s2 = (d ^ (d >> 3)) & 3;
            smem[VT2 + d * 96 + ((9 ^ s2) << 3) + 5 + t] = 0;
        }
    }
    // ---- zero P pad cols 80..95 ----
    #pragma unroll
    for (int i = 0; i < 4; i++) {
        int idx = tid + i * 256;
        int row = idx >> 4, col = 80 + (idx & 15);
        smem[PS2 + row * 104 + col] = 0;
    }
    __syncthreads();

    // ---- QK^T ----
    float s[5][4];
    __builtin_amdgcn_s_setprio(1);
    #pragma unroll
    for (int nt = 0; nt < 5; nt++) {
        bf16x8 bk0 = *(const bf16x8*)&smem[KS2 + (nt * 16 + l15) * 72 + koff];
        bf16x8 bk1 = *(const bf16x8*)&smem[KS2 + (nt * 16 + l15) * 72 + 32 + koff];
        f32x4 c = {0.f, 0.f, 0.f, 0.f};
        c = __builtin_amdgcn_mfma_f32_16x16x32_bf16(aq0, bk0, c, 0, 0, 0);
        c = __builtin_amdgcn_mfma_f32_16x16x32_bf16(aq1, bk1, c, 0, 0, 0);
        #pragma unroll
        for (int r = 0; r < 4; r++) s[nt][r] = c[r];
    }
    __builtin_amdgcn_s_setprio(0);
    if (l15 >= N_ - 64) {
        #pragma unroll
        for (int r = 0; r < 4; r++) s[4][r] = -1e30f;
    }
    // ---- softmax over n ----
    float li[4];
    #pragma unroll
    for (int r = 0; r < 4; r++) {
        float m = s[0][r];
        #pragma unroll
        for (int nt = 1; nt < 5; nt++) m = fmaxf(m, s[nt][r]);
        m = fmaxf(m, __shfl_xor(m, 1));
        m = fmaxf(m, __shfl_xor(m, 2));
        m = fmaxf(m, __shfl_xor(m, 4));
        m = fmaxf(m, __shfl_xor(m, 8));
        float l = 0.f;
        #pragma unroll
        for (int nt = 0; nt < 5; nt++) {
            float ev = __expf(s[nt][r] - m);
            s[nt][r] = ev;
            l += ev;
        }
        l += __shfl_xor(l, 1);
        l += __shfl_xor(l, 2);
        l += __shfl_xor(l, 4);
        l += __shfl_xor(l, 8);
        li[r] = 1.f / l;
    }
    #pragma unroll
    for (int r = 0; r < 4; r++) {
        int prow = w * 16 + quad * 4 + r;
        #pragma unroll
        for (int nt = 0; nt < 5; nt++) {
            smem[PS2 + prow * 104 + nt * 16 + l15] = f2b(s[nt][r] * li[r]);
        }
    }
    // within-wave LDS write->read: per-wave LDS ordering + compiler lgkmcnt

    bf16x8 pa0 = *(const bf16x8*)&smem[PS2 + mrow * 104 + 0  + koff];
    bf16x8 pa1 = *(const bf16x8*)&smem[PS2 + mrow * 104 + 32 + koff];
    bf16x8 pa2 = *(const bf16x8*)&smem[PS2 + mrow * 104 + 64 + koff];

    unsigned short* obase = yout + ((size_t)(b * T_ + t0 + w * 16)) * D_ + h * 64;
    #pragma unroll
    for (int dt = 0; dt < 4; dt++) {
        int drow = dt * 16 + l15;
        int s2 = (drow ^ (drow >> 3)) & 3;
        bf16x8 bv0 = *(const bf16x8*)&smem[VT2 + drow * 96 + (((0 + quad) ^ s2) << 3)];
        bf16x8 bv1 = *(const bf16x8*)&smem[VT2 + drow * 96 + (((4 + quad) ^ s2) << 3)];
        bf16x8 bv2 = *(const bf16x8*)&smem[VT2 + drow * 96 + (((8 + quad) ^ s2) << 3)];
        f32x4 c = {0.f, 0.f, 0.f, 0.f};
        __builtin_amdgcn_s_setprio(1);
        c = __builtin_amdgcn_mfma_f32_16x16x32_bf16(pa0, bv0, c, 0, 0, 0);
        c = __builtin_amdgcn_mfma_f32_16x16x32_bf16(pa1, bv1, c, 0, 0, 0);
        c = __builtin_amdgcn_mfma_f32_16x16x32_bf16(pa2, bv2, c, 0, 0, 0);
        __builtin_amdgcn_s_setprio(0);
        #pragma unroll
        for (int r = 0; r < 4; r++) {
            obase[(size_t)(quad * 4 + r) * D_ + dt * 16 + l15] = f2b(c[r]);
        }
    }
}

// ---------------------------------------------------------------------------
extern "C" void kernel_launch(void* const* d_in, const int* in_sizes, int n_in,
                              void* d_out, int out_size, void* d_ws, size_t ws_size,
                              hipStream_t stream)
{
    const float* x       = (const float*)d_in[0];
    const float* xf      = (const float*)d_in[1];
    const float* emb     = (const float*)d_in[2];
    const int*   cond    = (const int*)d_in[4];
    const float* norm_w  = (const float*)d_in[5];
    const float* norm_b  = (const float*)d_in[6];
    const float* tnorm_w = (const float*)d_in[7];
    const float* tnorm_b = (const float*)d_in[8];
    const float* Wq      = (const float*)d_in[9];
    const float* bq      = (const float*)d_in[10];
    const float* Wk      = (const float*)d_in[11];
    const float* bk      = (const float*)d_in[12];
    const float* Wv      = (const float*)d_in[13];
    const float* bv      = (const float*)d_in[14];
    const float* emb_w   = (const float*)d_in[15];
    const float* emb_b   = (const float*)d_in[16];
    const float* snorm_w = (const float*)d_in[17];
    const float* snorm_b = (const float*)d_in[18];
    const float* Wout    = (const float*)d_in[19];
    const float* bout    = (const float*)d_in[20];
    float* out = (float*)d_out;

    float* ws = (float*)d_ws;
    float* ebuf = ws;                                  // 32*1024 f32
    unsigned short* u = (unsigned short*)(ebuf + (size_t)B_ * 2 * D_);
    unsigned short* qyb  = u;  u += (size_t)B_ * T_ * D_;      // y bf16 (attn out)
    unsigned short* xfnb = u;  u += (size_t)2560 * TD_;        // LN(xf) bf16, padded rows
    unsigned short* kb16 = u;  u += (size_t)B_ * N_ * D_;      // K bf16
    unsigned short* vb16 = u;  u += (size_t)B_ * N_ * D_;      // V bf16 (gated)
    unsigned short* abh  = u;  u += (size_t)B_ * T_ * D_;      // bf16 A for big GEMMs
    unsigned short* wqb  = u;  u += (size_t)D_ * D_;
    unsigned short* wob  = u;  u += (size_t)D_ * D_;
    unsigned short* wkvb = u;  u += (size_t)2 * D_ * TD_;      // [Wk;Wv] bf16 [1024][256]
    unsigned short* qb = (unsigned short*)d_out;       // bf16 q scratch in d_out
                                                       // (dead before final GEMM overwrites)

    const int BT = B_ * T_;      // 32768

    // 1. merged prelude: prep_q + ln_xf + conv_weights + emb_gemm
    prelude_kernel<<<9704, 256, 0, stream>>>(
        x, norm_w, norm_b, abh,
        xf, tnorm_w, tnorm_b, xfnb,
        Wq, Wout, Wk, Wv, wqb, wob, wkvb,
        emb, emb_w, ebuf);
    // 2. merged projections: Q-GEMM (1024 blocks) + KV-GEMM (160 blocks)
    proj_kernel<<<1184, 256, 0, stream>>>(
        abh, wqb, bq, qb,
        xfnb, wkvb, bk, bv, cond, kb16, vb16);
    // 3. attention: qb/kb16/vb16 (bf16) -> y (bf16, qyb)
    {
        dim3 grid(T_ / 64, H_, B_);
        attn_mfma2_kernel<<<grid, 256, 0, stream>>>(qb, kb16, vb16, qyb);
    }
    // 4. prep A for out-GEMM: abh = bf16(silu(LN(y)*(1+sc)+sh))
    prep_h_kernel<<<BT / 4, 256, 0, stream>>>(qyb, snorm_w, snorm_b, ebuf, emb_b, abh);
    // 5. out projection (bf16 MFMA, fp32 out + residual): out = abh @ wob^T + bout + x
    gemm_bf16_kernel<1, 0><<<1024, 256, 0, stream>>>(abh, wob, bout, x, out);
}